// Round 9
// baseline (224.816 us; speedup 1.0000x reference)
//
#include <hip/hip_runtime.h>

typedef unsigned short ushort_t;
typedef __bf16 bf16x8 __attribute__((ext_vector_type(8)));
typedef float f32x4 __attribute__((ext_vector_type(4)));

// ---- problem constants ----
#define NPTS    49152    // B*R*SR
#define KNBR    8
#define PTS_A   8        // points per group -> 64 neighbor rows
#define PBLK_A  512      // persistent blocks (2/CU)
#define ITERS_A 12       // 512*12 = 6144 groups
#define PTS_B   32       // points per block, kernel B
#define NBLK_B  (NPTS / PTS_B)   // 1536

// ---- workspace layout (ushort elements) ----
// big weights: Wswz[(k/8)*256*8 + n*8 + (k%8)], K zero-padded
// final weights (N=16 pad): Wf[(k/8)*16*8 + n*8 + (k%8)], K=256
#define W1S_OFF   0         // K=44(+bias row 44) ->64
#define W2S_OFF   16384     // K=256
#define WA1S_OFF  81920     // K=256
#define WC1S_OFF  147456    // K=280 ->288
#define WA2S_OFF  221184    // 4096 (wa2 in col 0)
#define WC2S_OFF  225280    // 4096 (wc2 in cols 0..2)
#define WS_WEIGHT 229376
#define AGG_OFF   229376    // agg[49152][256] bf16 = 12.58M ushorts (25.2 MB)

__device__ __forceinline__ float b2f(ushort_t u) {
    return __builtin_bit_cast(float, ((unsigned)u) << 16);
}
// RNE f2b (prep only, cold path)
__device__ __forceinline__ ushort_t f2b(float f) {
    unsigned x = __builtin_bit_cast(unsigned, f);
    unsigned r = x + 0x7fffu + ((x >> 16) & 1u);
    return (ushort_t)(r >> 16);
}
// cheap round-half-up f2b (2 VALU ops, hot path)
__device__ __forceinline__ ushort_t f2bc(float f) {
    unsigned x = __builtin_bit_cast(unsigned, f);
    return (ushort_t)((x + 0x8000u) >> 16);
}

// ------------------------------------------------------------------
// prep: swizzle fp32 weights into bf16 MFMA-B fragment order.
// w1 gets b1 folded in at k==44 (input col 44 is constant 1.0).
// ------------------------------------------------------------------
__global__ __launch_bounds__(256) void prep_swizzle(
    const float* __restrict__ w1, const float* __restrict__ b1,
    const float* __restrict__ w2,
    const float* __restrict__ wa1, const float* __restrict__ wc1,
    const float* __restrict__ wa2, const float* __restrict__ wc2,
    ushort_t* __restrict__ ws)
{
    int idx = blockIdx.x * 256 + threadIdx.x;
    if (idx >= WS_WEIGHT) return;

    if (idx >= WA2S_OFF) {   // final-projection matrices, N=16 pad
        int off2 = idx - WA2S_OFF;
        int mat = off2 >> 12;          // 0: wa2, 1: wc2
        int off = off2 & 4095;
        int kb = off >> 7, rem = off & 127;
        int n = rem >> 3, j = rem & 7;
        int k = kb * 8 + j;
        float v = 0.f;
        if (mat == 0) { if (n == 0) v = wa2[k]; }
        else          { if (n < 3)  v = wc2[k * 3 + n]; }
        ws[idx] = f2b(v);
        return;
    }

    int off, base;
    if (idx < W2S_OFF) {   // w1 with bias fold
        off = idx; base = W1S_OFF;
        int kb = off >> 11, rem = off & 2047;
        int j = rem >> 8, n = rem & 255;
        int k = kb * 8 + j;
        float v = 0.f;
        if (k < 44)       v = w1[k * 256 + n];
        else if (k == 44) v = b1[n];
        ws[base + kb * 2048 + n * 8 + j] = f2b(v);
        return;
    }
    const float* src; int srcK;
    if (idx < WA1S_OFF)       { src = w2;  base = W2S_OFF;  off = idx - W2S_OFF;  srcK = 256; }
    else if (idx < WC1S_OFF)  { src = wa1; base = WA1S_OFF; off = idx - WA1S_OFF; srcK = 256; }
    else                      { src = wc1; base = WC1S_OFF; off = idx - WC1S_OFF; srcK = 280; }
    int kb  = off >> 11;
    int rem = off & 2047;
    int j = rem >> 8;
    int n = rem & 255;
    int k = kb * 8 + j;
    float v = (k < srcK) ? src[k * 256 + n] : 0.f;
    ws[base + kb * 2048 + n * 8 + j] = f2b(v);
}

// ------------------------------------------------------------------
// kernel A (persistent): per-neighbor MLP + weighted aggregation.
// 512 blocks x 12 iterations. Each wave register-caches its 32 w2
// B-fragments (128 VGPRs) ONCE; K-loops run from LDS-A + reg-B.
// 2 waves/SIMD (launch_bounds cap 256 VGPR).
// ------------------------------------------------------------------
__global__ __launch_bounds__(256, 2) void pa_mlp(
    const float* __restrict__ emb, const float* __restrict__ dists,
    const int* __restrict__ mask,  const float* __restrict__ b2,
    const ushort_t* __restrict__ ws, ushort_t* __restrict__ aggg)
{
    __shared__ __align__(16) ushort_t uH1[64 * 264];   // phase1: sFeat[64][72]; phase2: sH1[64][264]
    __shared__ __align__(16) float sWraw[64];
    __shared__ __align__(16) float sWn[64];
    ushort_t (*sFeat)[72] = (ushort_t(*)[72])uH1;
    ushort_t (*sH1)[264]  = (ushort_t(*)[264])uH1;

    const int tid  = threadIdx.x;
    const int lane = tid & 63;
    const int wv   = tid >> 6;
    const int n0   = lane & 15;
    const int quad = lane >> 4;
    const int colB = wv * 64;

    // ---- register-cache w2 B-fragments (once per kernel) ----
    bf16x8 w2c[32];
    #pragma unroll
    for (int ki = 0; ki < 8; ki++)
        #pragma unroll
        for (int nt = 0; nt < 4; nt++)
            w2c[ki * 4 + nt] = *(const bf16x8*)(ws + W2S_OFF + ki * 8192 + quad * 2048 + (colB + nt * 16 + n0) * 8);

    #pragma unroll 1
    for (int it = 0; it < ITERS_A; it++) {
        const int blk = blockIdx.x * ITERS_A + it;
        const int pb  = blk * PTS_A;

        // ---- staging ----
        {   // embedding: 2048 contiguous fp32 -> bf16 cols 0..31
            int g0 = blk * 2048 + tid * 8;
            int r = tid >> 2, c8 = (tid & 3) * 8;
            float4 f0 = *(const float4*)(emb + g0);
            float4 f1 = *(const float4*)(emb + g0 + 4);
            ushort_t v8[8];
            v8[0] = f2bc(f0.x); v8[1] = f2bc(f0.y); v8[2] = f2bc(f0.z); v8[3] = f2bc(f0.w);
            v8[4] = f2bc(f1.x); v8[5] = f2bc(f1.y); v8[6] = f2bc(f1.z); v8[7] = f2bc(f1.w);
            *(uint4*)&sFeat[r][c8] = *(uint4*)v8;
        }
        if (tid < 64) {   // dists -> raw weight + PE(dist,L=2) cols 32..43; col44=1 (bias); 45..63=0
            int gr = pb * KNBR + tid;
            float x = dists[gr * 3 + 0];
            float y = dists[gr * 3 + 1];
            float z = dists[gr * 3 + 2];
            float d2 = x * x + y * y + z * z;
            sWraw[tid] = (float)mask[gr] / fmaxf(d2, 1e-8f);
            float xs[3] = {x, y, z};
            #pragma unroll
            for (int d = 0; d < 3; d++) {
                #pragma unroll
                for (int l = 0; l < 2; l++) {
                    float ang = xs[d] * (float)(1 << l);
                    sFeat[tid][32 + d * 4 + l]     = f2bc(__sinf(ang));
                    sFeat[tid][32 + d * 4 + 2 + l] = f2bc(__cosf(ang));
                }
            }
            sFeat[tid][44] = 0x3F80;   // 1.0 -> multiplies folded b1 row
            #pragma unroll
            for (int c = 45; c < 64; c++) sFeat[tid][c] = 0;
        }
        __syncthreads();
        if (tid < 64) {
            int lp = tid >> 3;
            float s = 0.f;
            #pragma unroll
            for (int k = 0; k < 8; k++) s += sWraw[lp * 8 + k];
            sWn[tid] = sWraw[tid] / fmaxf(s, 1e-8f);
        }

        f32x4 acc[16];
        #pragma unroll
        for (int i = 0; i < 16; i++) acc[i] = (f32x4){0.f, 0.f, 0.f, 0.f};

        // ---- layer 1: K=64 (44 real + bias row), B streamed (L2-hot) ----
        #pragma unroll
        for (int ki = 0; ki < 2; ki++) {
            bf16x8 a[4];
            #pragma unroll
            for (int mt = 0; mt < 4; mt++)
                a[mt] = *(const bf16x8*)&sFeat[mt * 16 + n0][ki * 32 + quad * 8];
            const ushort_t* bp = ws + W1S_OFF + ki * 8192 + quad * 2048 + (colB + n0) * 8;
            #pragma unroll
            for (int nt = 0; nt < 4; nt++) {
                bf16x8 b = *(const bf16x8*)(bp + nt * 128);
                #pragma unroll
                for (int mt = 0; mt < 4; mt++)
                    acc[mt * 4 + nt] = __builtin_amdgcn_mfma_f32_16x16x32_bf16(a[mt], b, acc[mt * 4 + nt], 0, 0, 0);
            }
        }
        __syncthreads();   // sFeat reads done before overwrite

        {   // epilogue: relu only (bias folded) -> sH1
            #pragma unroll
            for (int nt = 0; nt < 4; nt++) {
                int col = colB + nt * 16 + n0;
                #pragma unroll
                for (int mt = 0; mt < 4; mt++)
                    #pragma unroll
                    for (int r = 0; r < 4; r++)
                        sH1[mt * 16 + quad * 4 + r][col] = f2bc(fmaxf(acc[mt * 4 + nt][r], 0.f));
            }
        }
        __syncthreads();

        // ---- layer 2: K=256, B from registers ----
        #pragma unroll
        for (int i = 0; i < 16; i++) acc[i] = (f32x4){0.f, 0.f, 0.f, 0.f};
        #pragma unroll
        for (int ki = 0; ki < 8; ki++) {
            bf16x8 a[4];
            #pragma unroll
            for (int mt = 0; mt < 4; mt++)
                a[mt] = *(const bf16x8*)&sH1[mt * 16 + n0][ki * 32 + quad * 8];
            #pragma unroll
            for (int nt = 0; nt < 4; nt++)
                #pragma unroll
                for (int mt = 0; mt < 4; mt++)
                    acc[mt * 4 + nt] = __builtin_amdgcn_mfma_f32_16x16x32_bf16(a[mt], w2c[ki * 4 + nt], acc[mt * 4 + nt], 0, 0, 0);
        }
        {   // epilogue: relu + neighbor-weighted sum -> global agg (bf16)
            #pragma unroll
            for (int mt = 0; mt < 4; mt++) {
                f32x4 wn4 = *(const f32x4*)&sWn[mt * 16 + quad * 4];
                #pragma unroll
                for (int nt = 0; nt < 4; nt++) {
                    int col = colB + nt * 16 + n0;
                    float bias = b2[col];
                    float s = fmaxf(acc[mt * 4 + nt][0] + bias, 0.f) * wn4[0]
                            + fmaxf(acc[mt * 4 + nt][1] + bias, 0.f) * wn4[1]
                            + fmaxf(acc[mt * 4 + nt][2] + bias, 0.f) * wn4[2]
                            + fmaxf(acc[mt * 4 + nt][3] + bias, 0.f) * wn4[3];
                    s += __shfl_xor(s, 16);
                    if ((quad & 1) == 0) {
                        int pt = pb + 2 * mt + (quad >> 1);
                        aggg[(size_t)pt * 256 + col] = f2bc(s);
                    }
                }
            }
        }
        __syncthreads();   // sH1/sWn reads done before next iter's staging
    }
}

// ------------------------------------------------------------------
// kernel B: branch MLPs, 32 points / block, 4 waves (unchanged).
// ------------------------------------------------------------------
__global__ __launch_bounds__(256) void pa_branch(
    const float* __restrict__ vdirs,
    const float* __restrict__ ba1v, const float* __restrict__ ba2v,
    const float* __restrict__ bc1v, const float* __restrict__ bc2v,
    const ushort_t* __restrict__ ws, const ushort_t* __restrict__ aggg,
    float* __restrict__ out)
{
    __shared__ __align__(16) ushort_t reg1[32 * 296];  // sCin; later sAh[32][264]
    __shared__ __align__(16) ushort_t reg2[32 * 264];  // sCh
    ushort_t (*sCin)[296] = (ushort_t(*)[296])reg1;
    ushort_t (*sAh)[264]  = (ushort_t(*)[264])reg1;
    ushort_t (*sCh)[264]  = (ushort_t(*)[264])reg2;

    const int tid  = threadIdx.x;
    const int lane = tid & 63;
    const int wv   = tid >> 6;
    const int n0   = lane & 15;
    const int quad = lane >> 4;
    const int pb   = blockIdx.x * PTS_B;
    const int colB = wv * 64;

    #pragma unroll
    for (int it = 0; it < 4; it++) {   // agg: 32*256 = 8192 ushorts
        int idx = (tid + it * 256) * 8;
        uint4 v = *(const uint4*)(aggg + (size_t)pb * 256 + idx);
        *(uint4*)&sCin[idx >> 8][idx & 255] = v;
    }
    #pragma unroll
    for (int it = 0; it < 3; it++) {   // PE(viewdirs,L=4): 32*24 = 768
        int t = tid + it * 256;
        int p = t / 24, j = t % 24;
        int d = j >> 3, jj = j & 7, l = jj & 3, isc = jj >> 2;
        float ang = vdirs[(pb + p) * 3 + d] * (float)(1 << l);
        sCin[p][256 + j] = f2bc(isc ? __cosf(ang) : __sinf(ang));
    }
    sCin[tid >> 3][280 + (tid & 7)] = 0;   // K-pad cols
    __syncthreads();

    f32x4 accA[8], accC[8];
    #pragma unroll
    for (int i = 0; i < 8; i++) { accA[i] = (f32x4){0.f, 0.f, 0.f, 0.f}; accC[i] = accA[i]; }

    // ---- alpha hidden: K=256 ----
    #pragma unroll
    for (int ki = 0; ki < 8; ki++) {
        bf16x8 a0 = *(const bf16x8*)&sCin[n0][ki * 32 + quad * 8];
        bf16x8 a1 = *(const bf16x8*)&sCin[16 + n0][ki * 32 + quad * 8];
        const ushort_t* bp = ws + WA1S_OFF + ki * 8192 + quad * 2048 + (colB + n0) * 8;
        #pragma unroll
        for (int nt = 0; nt < 4; nt++) {
            bf16x8 b = *(const bf16x8*)(bp + nt * 128);
            accA[nt]     = __builtin_amdgcn_mfma_f32_16x16x32_bf16(a0, b, accA[nt], 0, 0, 0);
            accA[4 + nt] = __builtin_amdgcn_mfma_f32_16x16x32_bf16(a1, b, accA[4 + nt], 0, 0, 0);
        }
    }
    // ---- color hidden: K=288 (280 real) ----
    #pragma unroll
    for (int ki = 0; ki < 9; ki++) {
        bf16x8 a0 = *(const bf16x8*)&sCin[n0][ki * 32 + quad * 8];
        bf16x8 a1 = *(const bf16x8*)&sCin[16 + n0][ki * 32 + quad * 8];
        const ushort_t* bp = ws + WC1S_OFF + ki * 8192 + quad * 2048 + (colB + n0) * 8;
        #pragma unroll
        for (int nt = 0; nt < 4; nt++) {
            bf16x8 b = *(const bf16x8*)(bp + nt * 128);
            accC[nt]     = __builtin_amdgcn_mfma_f32_16x16x32_bf16(a0, b, accC[nt], 0, 0, 0);
            accC[4 + nt] = __builtin_amdgcn_mfma_f32_16x16x32_bf16(a1, b, accC[4 + nt], 0, 0, 0);
        }
    }
    __syncthreads();

    #pragma unroll
    for (int nt = 0; nt < 4; nt++) {
        int col = colB + nt * 16 + n0;
        float biasA = ba1v[col];
        float biasC = bc1v[col];
        #pragma unroll
        for (int mt = 0; mt < 2; mt++)
            #pragma unroll
            for (int r = 0; r < 4; r++) {
                int row = mt * 16 + quad * 4 + r;
                sAh[row][col] = f2bc(fmaxf(accA[mt * 4 + nt][r] + biasA, 0.f));
                sCh[row][col] = f2bc(fmaxf(accC[mt * 4 + nt][r] + biasC, 0.f));
            }
    }
    __syncthreads();

    // ---- finals via MFMA ----
    {
        const int isColor = wv >> 1;
        const int baseM   = (wv & 1) * 16;
        const ushort_t* A = isColor ? &sCh[0][0] : &sAh[0][0];
        const ushort_t* B = ws + (isColor ? WC2S_OFF : WA2S_OFF);
        f32x4 acc4 = (f32x4){0.f, 0.f, 0.f, 0.f};
        #pragma unroll
        for (int ki = 0; ki < 8; ki++) {
            bf16x8 a = *(const bf16x8*)(A + (baseM + n0) * 264 + ki * 32 + quad * 8);
            bf16x8 b = *(const bf16x8*)(B + ki * 512 + quad * 128 + n0 * 8);
            acc4 = __builtin_amdgcn_mfma_f32_16x16x32_bf16(a, b, acc4, 0, 0, 0);
        }
        if (!isColor) {
            if (n0 == 0) {
                float ba2s = ba2v[0];
                #pragma unroll
                for (int r = 0; r < 4; r++) {
                    int gp = pb + baseM + quad * 4 + r;
                    float yv = acc4[r] + ba2s - 1.0f;
                    out[(size_t)gp * 4] = (yv > 20.f) ? yv : log1pf(expf(yv));
                }
            }
        } else {
            if (n0 < 3) {
                float bc2s = bc2v[n0];
                #pragma unroll
                for (int r = 0; r < 4; r++) {
                    int gp = pb + baseM + quad * 4 + r;
                    float sig = 1.f / (1.f + expf(-(acc4[r] + bc2s)));
                    out[(size_t)gp * 4 + 1 + n0] = sig * (1.0f + 2e-3f) - 1e-3f;
                }
            }
        }
    }
}

extern "C" void kernel_launch(void* const* d_in, const int* in_sizes, int n_in,
                              void* d_out, int out_size, void* d_ws, size_t ws_size,
                              hipStream_t stream) {
    const float* emb   = (const float*)d_in[0];
    const float* dists = (const float*)d_in[1];
    const float* vdir  = (const float*)d_in[2];
    const int*   mask  = (const int*)d_in[3];
    const float* w1    = (const float*)d_in[4];
    const float* b1    = (const float*)d_in[5];
    const float* w2    = (const float*)d_in[6];
    const float* b2    = (const float*)d_in[7];
    const float* wa1   = (const float*)d_in[8];
    const float* ba1   = (const float*)d_in[9];
    const float* wa2   = (const float*)d_in[10];
    const float* ba2   = (const float*)d_in[11];
    const float* wc1   = (const float*)d_in[12];
    const float* bc1   = (const float*)d_in[13];
    const float* wc2   = (const float*)d_in[14];
    const float* bc2   = (const float*)d_in[15];
    ushort_t* ws  = (ushort_t*)d_ws;
    float*    out = (float*)d_out;

    prep_swizzle<<<dim3((WS_WEIGHT + 255) / 256), dim3(256), 0, stream>>>(
        w1, b1, w2, wa1, wc1, wa2, wc2, ws);
    pa_mlp<<<dim3(PBLK_A), dim3(256), 0, stream>>>(
        emb, dists, mask, b2, ws, ws + AGG_OFF);
    pa_branch<<<dim3(NBLK_B), dim3(256), 0, stream>>>(
        vdir, ba1, ba2, bc1, bc2, ws, ws + AGG_OFF, out);
}

// Round 11
// 223.039 us; speedup vs baseline: 1.0080x; 1.0080x over previous
//
#include <hip/hip_runtime.h>

typedef unsigned short ushort_t;
typedef __bf16 bf16x8 __attribute__((ext_vector_type(8)));
typedef float f32x4 __attribute__((ext_vector_type(4)));

// ---- problem constants ----
#define NPTS    49152    // B*R*SR
#define KNBR    8
#define PTS_A   8        // points per block, kernel A -> 64 neighbor rows
#define NBLK_A  (NPTS / PTS_A)   // 6144
#define PTS_B   32       // points per block, kernel B
#define NBLK_B  (NPTS / PTS_B)   // 1536

// ---- workspace layout (ushort elements) ----
// big weights: Wswz[(k/8)*256*8 + n*8 + (k%8)], K zero-padded
// final weights (N=16 pad): Wf[(k/8)*16*8 + n*8 + (k%8)], K=256
#define W1S_OFF   0         // K=44(+b1 row 44) ->64
#define W2S_OFF   16384     // K=256
#define WA1S_OFF  81920     // K=256
#define WC1S_OFF  147456    // K=280 ->288
#define WA2S_OFF  221184    // 4096 (wa2 in col 0)
#define WC2S_OFF  225280    // 4096 (wc2 in cols 0..2)
#define WS_WEIGHT 229376
#define AGG_OFF   229376    // agg[49152][256] bf16 = 12.58M ushorts (25.2 MB)

__device__ __forceinline__ float b2f(ushort_t u) {
    return __builtin_bit_cast(float, ((unsigned)u) << 16);
}
// RNE f2b (prep only, cold path)
__device__ __forceinline__ ushort_t f2b(float f) {
    unsigned x = __builtin_bit_cast(unsigned, f);
    unsigned r = x + 0x7fffu + ((x >> 16) & 1u);
    return (ushort_t)(r >> 16);
}
// cheap round-half-up f2b (2 VALU ops, hot path)
__device__ __forceinline__ ushort_t f2bc(float f) {
    unsigned x = __builtin_bit_cast(unsigned, f);
    return (ushort_t)((x + 0x8000u) >> 16);
}

// ------------------------------------------------------------------
// prep: swizzle fp32 weights into bf16 MFMA-B fragment order.
// w1 gets b1 folded at k==44 (input col 44 is constant 1.0).
// ------------------------------------------------------------------
__global__ __launch_bounds__(256) void prep_swizzle(
    const float* __restrict__ w1, const float* __restrict__ b1,
    const float* __restrict__ w2,
    const float* __restrict__ wa1, const float* __restrict__ wc1,
    const float* __restrict__ wa2, const float* __restrict__ wc2,
    ushort_t* __restrict__ ws)
{
    int idx = blockIdx.x * 256 + threadIdx.x;
    if (idx >= WS_WEIGHT) return;

    if (idx >= WA2S_OFF) {   // final-projection matrices, N=16 pad
        int off2 = idx - WA2S_OFF;
        int mat = off2 >> 12;          // 0: wa2, 1: wc2
        int off = off2 & 4095;
        int kb = off >> 7, rem = off & 127;
        int n = rem >> 3, j = rem & 7;
        int k = kb * 8 + j;
        float v = 0.f;
        if (mat == 0) { if (n == 0) v = wa2[k]; }
        else          { if (n < 3)  v = wc2[k * 3 + n]; }
        ws[idx] = f2b(v);
        return;
    }

    if (idx < W2S_OFF) {   // w1 with b1 fold
        int kb = idx >> 11, rem = idx & 2047;
        int j = rem >> 8, n = rem & 255;
        int k = kb * 8 + j;
        float v = 0.f;
        if (k < 44)       v = w1[k * 256 + n];
        else if (k == 44) v = b1[n];
        ws[W1S_OFF + kb * 2048 + n * 8 + j] = f2b(v);
        return;
    }
    const float* src; int off, srcK, base;
    if (idx < WA1S_OFF)       { src = w2;  base = W2S_OFF;  off = idx - W2S_OFF;  srcK = 256; }
    else if (idx < WC1S_OFF)  { src = wa1; base = WA1S_OFF; off = idx - WA1S_OFF; srcK = 256; }
    else                      { src = wc1; base = WC1S_OFF; off = idx - WC1S_OFF; srcK = 280; }
    int kb  = off >> 11;
    int rem = off & 2047;
    int j = rem >> 8;
    int n = rem & 255;
    int k = kb * 8 + j;
    float v = (k < srcK) ? src[k * 256 + n] : 0.f;
    ws[base + kb * 2048 + n * 8 + j] = f2b(v);
}

// ------------------------------------------------------------------
// kernel A (round-8 structure + b1 fold): per-neighbor MLP +
// weighted aggregation. 8 points (64 rows) / block, 4 waves,
// N-split; sH1 aliases sFeat. 34.3 KB LDS -> 4 blocks/CU.
// ------------------------------------------------------------------
__global__ __launch_bounds__(256) void pa_mlp(
    const float* __restrict__ emb, const float* __restrict__ dists,
    const int* __restrict__ mask,  const float* __restrict__ b2,
    const ushort_t* __restrict__ ws, ushort_t* __restrict__ aggg)
{
    __shared__ __align__(16) ushort_t uH1[64 * 264];   // phase1: sFeat[64][72]; phase2: sH1[64][264]
    __shared__ __align__(16) float sWraw[64];
    __shared__ __align__(16) float sWn[64];
    ushort_t (*sFeat)[72] = (ushort_t(*)[72])uH1;
    ushort_t (*sH1)[264]  = (ushort_t(*)[264])uH1;

    const int tid  = threadIdx.x;
    const int lane = tid & 63;
    const int wv   = tid >> 6;
    const int n0   = lane & 15;
    const int quad = lane >> 4;
    const int pb   = blockIdx.x * PTS_A;
    const int colB = wv * 64;

    {   // embedding: 2048 contiguous fp32 per block -> bf16 cols 0..31
        int g0 = blockIdx.x * 2048 + tid * 8;
        int r = tid >> 2, c8 = (tid & 3) * 8;
        float4 f0 = *(const float4*)(emb + g0);
        float4 f1 = *(const float4*)(emb + g0 + 4);
        ushort_t v8[8];
        v8[0] = f2bc(f0.x); v8[1] = f2bc(f0.y); v8[2] = f2bc(f0.z); v8[3] = f2bc(f0.w);
        v8[4] = f2bc(f1.x); v8[5] = f2bc(f1.y); v8[6] = f2bc(f1.z); v8[7] = f2bc(f1.w);
        *(uint4*)&sFeat[r][c8] = *(uint4*)v8;
    }
    if (tid < 64) {   // dists -> raw weight + PE(dist,L=2) cols 32..43; col44=1 (b1); 45..63=0
        int gr = pb * KNBR + tid;
        float x = dists[gr * 3 + 0];
        float y = dists[gr * 3 + 1];
        float z = dists[gr * 3 + 2];
        float d2 = x * x + y * y + z * z;
        sWraw[tid] = (float)mask[gr] / fmaxf(d2, 1e-8f);
        float xs[3] = {x, y, z};
        #pragma unroll
        for (int d = 0; d < 3; d++) {
            #pragma unroll
            for (int l = 0; l < 2; l++) {
                float ang = xs[d] * (float)(1 << l);
                sFeat[tid][32 + d * 4 + l]     = f2bc(__sinf(ang));
                sFeat[tid][32 + d * 4 + 2 + l] = f2bc(__cosf(ang));
            }
        }
        sFeat[tid][44] = 0x3F80;   // 1.0 -> multiplies folded b1 row
        #pragma unroll
        for (int c = 45; c < 64; c++) sFeat[tid][c] = 0;
    }
    __syncthreads();
    if (tid < 64) {   // read only in epilogue-2 (after 2 more barriers)
        int lp = tid >> 3;
        float s = 0.f;
        #pragma unroll
        for (int k = 0; k < 8; k++) s += sWraw[lp * 8 + k];
        sWn[tid] = sWraw[tid] / fmaxf(s, 1e-8f);
    }

    f32x4 acc[16];
    #pragma unroll
    for (int i = 0; i < 16; i++) acc[i] = (f32x4){0.f, 0.f, 0.f, 0.f};

    // ---- layer 1: K=64 (44 real + bias row) ----
    #pragma unroll
    for (int ki = 0; ki < 2; ki++) {
        bf16x8 a[4];
        #pragma unroll
        for (int mt = 0; mt < 4; mt++)
            a[mt] = *(const bf16x8*)&sFeat[mt * 16 + n0][ki * 32 + quad * 8];
        const ushort_t* bp = ws + W1S_OFF + ki * 8192 + quad * 2048 + (colB + n0) * 8;
        #pragma unroll
        for (int nt = 0; nt < 4; nt++) {
            bf16x8 b = *(const bf16x8*)(bp + nt * 128);
            #pragma unroll
            for (int mt = 0; mt < 4; mt++)
                acc[mt * 4 + nt] = __builtin_amdgcn_mfma_f32_16x16x32_bf16(a[mt], b, acc[mt * 4 + nt], 0, 0, 0);
        }
    }
    __syncthreads();   // sFeat reads done before overwrite

    {   // epilogue: relu only (bias folded) -> sH1
        #pragma unroll
        for (int nt = 0; nt < 4; nt++) {
            int col = colB + nt * 16 + n0;
            #pragma unroll
            for (int mt = 0; mt < 4; mt++)
                #pragma unroll
                for (int r = 0; r < 4; r++)
                    sH1[mt * 16 + quad * 4 + r][col] = f2bc(fmaxf(acc[mt * 4 + nt][r], 0.f));
        }
    }
    __syncthreads();

    // ---- layer 2: K=256, B streamed (L2-hot) ----
    #pragma unroll
    for (int i = 0; i < 16; i++) acc[i] = (f32x4){0.f, 0.f, 0.f, 0.f};
    #pragma unroll
    for (int ki = 0; ki < 8; ki++) {
        bf16x8 a[4];
        #pragma unroll
        for (int mt = 0; mt < 4; mt++)
            a[mt] = *(const bf16x8*)&sH1[mt * 16 + n0][ki * 32 + quad * 8];
        const ushort_t* bp = ws + W2S_OFF + ki * 8192 + quad * 2048 + (colB + n0) * 8;
        #pragma unroll
        for (int nt = 0; nt < 4; nt++) {
            bf16x8 b = *(const bf16x8*)(bp + nt * 128);
            #pragma unroll
            for (int mt = 0; mt < 4; mt++)
                acc[mt * 4 + nt] = __builtin_amdgcn_mfma_f32_16x16x32_bf16(a[mt], b, acc[mt * 4 + nt], 0, 0, 0);
        }
    }
    {   // epilogue: relu + neighbor-weighted sum -> global agg (bf16)
        #pragma unroll
        for (int mt = 0; mt < 4; mt++) {
            f32x4 wn4 = *(const f32x4*)&sWn[mt * 16 + quad * 4];
            #pragma unroll
            for (int nt = 0; nt < 4; nt++) {
                int col = colB + nt * 16 + n0;
                float bias = b2[col];
                float s = fmaxf(acc[mt * 4 + nt][0] + bias, 0.f) * wn4[0]
                        + fmaxf(acc[mt * 4 + nt][1] + bias, 0.f) * wn4[1]
                        + fmaxf(acc[mt * 4 + nt][2] + bias, 0.f) * wn4[2]
                        + fmaxf(acc[mt * 4 + nt][3] + bias, 0.f) * wn4[3];
                s += __shfl_xor(s, 16);
                if ((quad & 1) == 0) {
                    int pt = pb + 2 * mt + (quad >> 1);
                    aggg[(size_t)pt * 256 + col] = f2bc(s);
                }
            }
        }
    }
}

// ------------------------------------------------------------------
// kernel B: branch MLPs, 32 points / block, 512 threads (8 waves).
// Waves 0-3: alpha hidden (64-col chunks); waves 4-7: color hidden.
// sAh aliases dead sCin; finals via MFMA.
// ------------------------------------------------------------------
__global__ __launch_bounds__(512) void pa_branch(
    const float* __restrict__ vdirs,
    const float* __restrict__ ba1v, const float* __restrict__ ba2v,
    const float* __restrict__ bc1v, const float* __restrict__ bc2v,
    const ushort_t* __restrict__ ws, const ushort_t* __restrict__ aggg,
    float* __restrict__ out)
{
    __shared__ __align__(16) ushort_t reg1[32 * 296];  // sCin; later sAh[32][264]
    __shared__ __align__(16) ushort_t reg2[32 * 264];  // sCh
    ushort_t (*sCin)[296] = (ushort_t(*)[296])reg1;
    ushort_t (*sAh)[264]  = (ushort_t(*)[264])reg1;
    ushort_t (*sCh)[264]  = (ushort_t(*)[264])reg2;

    const int tid  = threadIdx.x;
    const int lane = tid & 63;
    const int wv   = tid >> 6;        // 0..7
    const int sub  = wv & 3;
    const int isColor = wv >> 2;
    const int n0   = lane & 15;
    const int quad = lane >> 4;
    const int pb   = blockIdx.x * PTS_B;
    const int colB = sub * 64;

    // ---- staging ----
    #pragma unroll
    for (int it = 0; it < 2; it++) {   // agg: 32*256 = 8192 ushorts = 1024 uint4
        int idx = (tid + it * 512) * 8;
        uint4 v = *(const uint4*)(aggg + (size_t)pb * 256 + idx);
        *(uint4*)&sCin[idx >> 8][idx & 255] = v;
    }
    #pragma unroll
    for (int it = 0; it < 2; it++) {   // PE(viewdirs,L=4): 32*24 = 768 entries
        int t = tid + it * 512;
        if (t < 768) {
            int p = t / 24, j = t % 24;
            int d = j >> 3, jj = j & 7, l = jj & 3, isc = jj >> 2;
            float ang = vdirs[(pb + p) * 3 + d] * (float)(1 << l);
            sCin[p][256 + j] = f2bc(isc ? __cosf(ang) : __sinf(ang));
        }
    }
    if (tid < 256) sCin[tid >> 3][280 + (tid & 7)] = 0;   // K-pad cols
    __syncthreads();

    // ---- hidden layer (per wave group): K=256 alpha / K=288 color ----
    f32x4 acc[8];   // [mt 0..1][nt 0..3]
    #pragma unroll
    for (int i = 0; i < 8; i++) acc[i] = (f32x4){0.f, 0.f, 0.f, 0.f};
    const int wOff = isColor ? WC1S_OFF : WA1S_OFF;
    #pragma unroll
    for (int ki = 0; ki < 8; ki++) {
        bf16x8 a0 = *(const bf16x8*)&sCin[n0][ki * 32 + quad * 8];
        bf16x8 a1 = *(const bf16x8*)&sCin[16 + n0][ki * 32 + quad * 8];
        const ushort_t* bp = ws + wOff + ki * 8192 + quad * 2048 + (colB + n0) * 8;
        #pragma unroll
        for (int nt = 0; nt < 4; nt++) {
            bf16x8 b = *(const bf16x8*)(bp + nt * 128);
            acc[nt]     = __builtin_amdgcn_mfma_f32_16x16x32_bf16(a0, b, acc[nt], 0, 0, 0);
            acc[4 + nt] = __builtin_amdgcn_mfma_f32_16x16x32_bf16(a1, b, acc[4 + nt], 0, 0, 0);
        }
    }
    if (isColor) {   // color K-block 8 (cols 256..287: PE + pad)
        bf16x8 a0 = *(const bf16x8*)&sCin[n0][256 + quad * 8];
        bf16x8 a1 = *(const bf16x8*)&sCin[16 + n0][256 + quad * 8];
        const ushort_t* bp = ws + WC1S_OFF + 8 * 8192 + quad * 2048 + (colB + n0) * 8;
        #pragma unroll
        for (int nt = 0; nt < 4; nt++) {
            bf16x8 b = *(const bf16x8*)(bp + nt * 128);
            acc[nt]     = __builtin_amdgcn_mfma_f32_16x16x32_bf16(a0, b, acc[nt], 0, 0, 0);
            acc[4 + nt] = __builtin_amdgcn_mfma_f32_16x16x32_bf16(a1, b, acc[4 + nt], 0, 0, 0);
        }
    }
    __syncthreads();   // all sCin reads complete before sAh overwrites it

    {   // epilogue: bias + relu -> sAh (alpha waves) / sCh (color waves)
        const float* bv = isColor ? bc1v : ba1v;
        ushort_t* dst = isColor ? &sCh[0][0] : &sAh[0][0];
        #pragma unroll
        for (int nt = 0; nt < 4; nt++) {
            int col = colB + nt * 16 + n0;
            float bias = bv[col];
            #pragma unroll
            for (int mt = 0; mt < 2; mt++)
                #pragma unroll
                for (int r = 0; r < 4; r++) {
                    int row = mt * 16 + quad * 4 + r;
                    dst[row * 264 + col] = f2bc(fmaxf(acc[mt * 4 + nt][r] + bias, 0.f));
                }
        }
    }
    __syncthreads();

    // ---- finals via MFMA: sub<2 waves of each group, m-tile = sub ----
    if (sub < 2) {
        const ushort_t* A = isColor ? &sCh[0][0] : &sAh[0][0];
        const ushort_t* B = ws + (isColor ? WC2S_OFF : WA2S_OFF);
        f32x4 acc4 = (f32x4){0.f, 0.f, 0.f, 0.f};
        #pragma unroll
        for (int ki = 0; ki < 8; ki++) {
            bf16x8 a = *(const bf16x8*)(A + (sub * 16 + n0) * 264 + ki * 32 + quad * 8);
            bf16x8 b = *(const bf16x8*)(B + ki * 512 + quad * 128 + n0 * 8);
            acc4 = __builtin_amdgcn_mfma_f32_16x16x32_bf16(a, b, acc4, 0, 0, 0);
        }
        if (!isColor) {
            if (n0 == 0) {
                float ba2s = ba2v[0];
                #pragma unroll
                for (int r = 0; r < 4; r++) {
                    int gp = pb + sub * 16 + quad * 4 + r;
                    float yv = acc4[r] + ba2s - 1.0f;
                    out[(size_t)gp * 4] = (yv > 20.f) ? yv : log1pf(expf(yv));
                }
            }
        } else {
            if (n0 < 3) {
                float bc2s = bc2v[n0];
                #pragma unroll
                for (int r = 0; r < 4; r++) {
                    int gp = pb + sub * 16 + quad * 4 + r;
                    float sig = 1.f / (1.f + expf(-(acc4[r] + bc2s)));
                    out[(size_t)gp * 4 + 1 + n0] = sig * (1.0f + 2e-3f) - 1e-3f;
                }
            }
        }
    }
}

extern "C" void kernel_launch(void* const* d_in, const int* in_sizes, int n_in,
                              void* d_out, int out_size, void* d_ws, size_t ws_size,
                              hipStream_t stream) {
    const float* emb   = (const float*)d_in[0];
    const float* dists = (const float*)d_in[1];
    const float* vdir  = (const float*)d_in[2];
    const int*   mask  = (const int*)d_in[3];
    const float* w1    = (const float*)d_in[4];
    const float* b1    = (const float*)d_in[5];
    const float* w2    = (const float*)d_in[6];
    const float* b2    = (const float*)d_in[7];
    const float* wa1   = (const float*)d_in[8];
    const float* ba1   = (const float*)d_in[9];
    const float* wa2   = (const float*)d_in[10];
    const float* ba2   = (const float*)d_in[11];
    const float* wc1   = (const float*)d_in[12];
    const float* bc1   = (const float*)d_in[13];
    const float* wc2   = (const float*)d_in[14];
    const float* bc2   = (const float*)d_in[15];
    ushort_t* ws  = (ushort_t*)d_ws;
    float*    out = (float*)d_out;

    prep_swizzle<<<dim3((WS_WEIGHT + 255) / 256), dim3(256), 0, stream>>>(
        w1, b1, w2, wa1, wc1, wa2, wc2, ws);
    pa_mlp<<<dim3(NBLK_A), dim3(256), 0, stream>>>(
        emb, dists, mask, b2, ws, ws + AGG_OFF);
    pa_branch<<<dim3(NBLK_B), dim3(512), 0, stream>>>(
        vdir, ba1, ba2, bc1, bc2, ws, ws + AGG_OFF, out);
}